// Round 6
// baseline (1979.228 us; speedup 1.0000x reference)
//
#include <hip/hip_runtime.h>
#include <math.h>

#define BB 64
#define TT 1024
#define II 256
#define HD 256

typedef unsigned short ushort_t;
typedef unsigned int uint_t;

// MFMA fragment types
typedef short sh8 __attribute__((ext_vector_type(8)));
typedef float fx4 __attribute__((ext_vector_type(4)));
typedef uint_t u32x4 __attribute__((ext_vector_type(4)));
typedef __bf16 v2bf __attribute__((ext_vector_type(2)));

// ---- bf16 helpers (manual, RNE) -------------------------------------------
__device__ __forceinline__ ushort_t f2bf(float f) {
    uint_t u = __float_as_uint(f);
    uint_t r = (u + 0x7fffu + ((u >> 16) & 1u)) >> 16;
    return (ushort_t)r;
}
__device__ __forceinline__ float bf2f(ushort_t v) {
    return __uint_as_float(((uint_t)v) << 16);
}

// packed-pair bf16 dot: acc += w.lo*h.lo + w.hi*h.hi  (r0-proven)
__device__ __forceinline__ float dot2bf(uint_t w, uint_t h, float acc) {
#if __has_builtin(__builtin_amdgcn_fdot2_f32_bf16)
    return __builtin_amdgcn_fdot2_f32_bf16(__builtin_bit_cast(v2bf, w),
                                           __builtin_bit_cast(v2bf, h), acc, false);
#else
    acc += __uint_as_float(w << 16) * __uint_as_float(h << 16);
    acc += __uint_as_float(w & 0xffff0000u) * __uint_as_float(h & 0xffff0000u);
    return acc;
#endif
}

__device__ __forceinline__ float fast_rcp(float x) {
#if __has_builtin(__builtin_amdgcn_rcpf)
    return __builtin_amdgcn_rcpf(x);
#else
    return 1.f / x;
#endif
}
__device__ __forceinline__ float sigm(float x) {
    return fast_rcp(1.f + __expf(-x));
}
__device__ __forceinline__ float tanh_fast(float x) {
    return 1.f - 2.f * fast_rcp(1.f + __expf(2.f * x));
}

__device__ __forceinline__ fx4 mfma16(sh8 a, sh8 b, fx4 c) {
    return __builtin_amdgcn_mfma_f32_16x16x32_bf16(a, b, c, 0, 0, 0);
}

// split fp32 pair -> bf16 hi (trunc) + bf16 lo (residual) packed u32s
__device__ __forceinline__ void split2(float a, float b, uint_t& hi, uint_t& lo) {
    const uint_t ua = __float_as_uint(a), ub = __float_as_uint(b);
    hi = (ua >> 16) | (ub & 0xffff0000u);
    const float la = a - __uint_as_float(ua & 0xffff0000u);
    const float lb = b - __uint_as_float(ub & 0xffff0000u);
    const uint_t ula = __float_as_uint(la), ulb = __float_as_uint(lb);
    lo = (ula >> 16) | (ulb & 0xffff0000u);
}

// async global->LDS, 16B per lane
__device__ __forceinline__ void async_g2l(const ushort_t* g, ushort_t* l) {
#if __has_builtin(__builtin_amdgcn_global_load_lds)
    __builtin_amdgcn_global_load_lds(
        (const __attribute__((address_space(1))) unsigned int*)g,
        (__attribute__((address_space(3))) unsigned int*)l, 16, 0, 0);
#else
    *reinterpret_cast<uint4*>(l) = *reinterpret_cast<const uint4*>(g);
#endif
}

#define BAR() asm volatile("s_waitcnt lgkmcnt(0)\n\ts_barrier" ::: "memory")

// ---------------------------------------------------------------------------
// Kernel 0: prepack weights.
//  y=0..2: recurrent W fp32 [k][j] ->
//      (a) bf16 W^T rows  T[j*256+k]          (MFMA B-frags, K<128 used)
//      (b) pair-packed    P[p*256+j] = (bf16 W[2p+1][j])<<16 | bf16 W[2p][j]
//          (VALU dot2 path, pairs p>=64 used)
//  y=3..5: input Wx fp32 -> split bf16 hi/lo W^T (proj_mfma)
// ---------------------------------------------------------------------------
__global__ __launch_bounds__(256) void prepack_kernel(
    const float* __restrict__ Wz, const float* __restrict__ Wr,
    const float* __restrict__ Wh,
    const float* __restrict__ Xz, const float* __restrict__ Xr,
    const float* __restrict__ Xh,
    ushort_t* __restrict__ Tz, ushort_t* __restrict__ Tr,
    ushort_t* __restrict__ Th,
    uint_t* __restrict__ Pz, uint_t* __restrict__ Pr, uint_t* __restrict__ Ph,
    ushort_t* __restrict__ Thi, ushort_t* __restrict__ Tlo)
{
    const int idx = blockIdx.x * 256 + threadIdx.x;  // 0..65535
    const int y = blockIdx.y;
    if (y < 3) {
        const float* W = (y == 0) ? Wz : (y == 1) ? Wr : Wh;
        ushort_t* T = (y == 0) ? Tz : (y == 1) ? Tr : Th;
        uint_t* P = (y == 0) ? Pz : (y == 1) ? Pr : Ph;
        const int j = idx >> 8;
        const int k = idx & 255;
        T[idx] = f2bf(W[k * HD + j]);
        if (idx < 32768) {
            const int p = idx >> 8;
            const int jj = idx & 255;
            const ushort_t lo = f2bf(W[(2 * p) * HD + jj]);
            const ushort_t hi = f2bf(W[(2 * p + 1) * HD + jj]);
            P[idx] = ((uint_t)hi << 16) | lo;
        }
    } else {
        const int g = y - 3;
        const float* W = (g == 0) ? Xz : (g == 1) ? Xr : Xh;
        const int j = idx >> 8;
        const int k = idx & 255;
        const float wv = W[k * HD + j];
        const ushort_t hi = f2bf(wv);
        Thi[g * 65536 + idx] = hi;
        Tlo[g * 65536 + idx] = f2bf(wv - bf2f(hi));
    }
}

// ---------------------------------------------------------------------------
// Kernel 1: input projection as 3-term split-precision bf16 MFMA GEMM.
// (unchanged from r5 — verified)
// ---------------------------------------------------------------------------
__global__ __launch_bounds__(256) void proj_mfma(
    const float* __restrict__ X,
    const ushort_t* __restrict__ Thi, const ushort_t* __restrict__ Tlo,
    const float* __restrict__ bz, const float* __restrict__ br,
    const float* __restrict__ bh,
    ushort_t* __restrict__ x5)
{
    __shared__ __align__(16) ushort_t ep[64 * 256];  // 32KB

    const int tid  = threadIdx.x;
    const int lane = tid & 63;
    const int w    = tid >> 6;
    const int kq   = lane >> 4;
    const int ml   = lane & 15;
    const int m0   = blockIdx.x * 64;
    const int g    = blockIdx.y;

    const ushort_t* Bh = Thi + (size_t)g * 65536;
    const ushort_t* Bl = Tlo + (size_t)g * 65536;
    const float* bias = (g == 0) ? bz : (g == 1) ? br : bh;

    const fx4 zero4 = {0.f, 0.f, 0.f, 0.f};
    fx4 acc[4][4];
#pragma unroll
    for (int mt = 0; mt < 4; ++mt)
#pragma unroll
        for (int nt = 0; nt < 4; ++nt) acc[mt][nt] = zero4;

    for (int kt = 0; kt < 8; ++kt) {
        const int koff = kq * 8 + kt * 32;
        sh8 bhi[4], blo[4];
#pragma unroll
        for (int nt = 0; nt < 4; ++nt) {
            const size_t rb = (size_t)(w * 64 + nt * 16 + ml) * 256 + koff;
            bhi[nt] = *reinterpret_cast<const sh8*>(Bh + rb);
            blo[nt] = *reinterpret_cast<const sh8*>(Bl + rb);
        }
#pragma unroll
        for (int mt = 0; mt < 4; ++mt) {
            const float* xp = X + (size_t)(m0 + mt * 16 + ml) * II + koff;
            const float4 f0 = *reinterpret_cast<const float4*>(xp);
            const float4 f1 = *reinterpret_cast<const float4*>(xp + 4);
            uint_t hv0, hv1, hv2, hv3, lv0, lv1, lv2, lv3;
            split2(f0.x, f0.y, hv0, lv0);
            split2(f0.z, f0.w, hv1, lv1);
            split2(f1.x, f1.y, hv2, lv2);
            split2(f1.z, f1.w, hv3, lv3);
            const u32x4 hq = {hv0, hv1, hv2, hv3};
            const u32x4 lq = {lv0, lv1, lv2, lv3};
            const sh8 ahi = __builtin_bit_cast(sh8, hq);
            const sh8 alo = __builtin_bit_cast(sh8, lq);
#pragma unroll
            for (int nt = 0; nt < 4; ++nt) {
                acc[mt][nt] = mfma16(ahi, bhi[nt], acc[mt][nt]);
                acc[mt][nt] = mfma16(alo, bhi[nt], acc[mt][nt]);
                acc[mt][nt] = mfma16(ahi, blo[nt], acc[mt][nt]);
            }
        }
    }

#pragma unroll
    for (int nt = 0; nt < 4; ++nt) {
        const int col = w * 64 + nt * 16 + ml;
        const float bv = bias[col];
#pragma unroll
        for (int mt = 0; mt < 4; ++mt)
#pragma unroll
            for (int r = 0; r < 4; ++r)
                ep[(mt * 16 + kq * 4 + r) * 256 + col] =
                    f2bf(acc[mt][nt][r] + bv);
    }
    __syncthreads();

    const int b   = m0 >> 10;
    const int t0m = m0 & 1023;
    const uint4* eps = reinterpret_cast<const uint4*>(ep);
#pragma unroll
    for (int it = 0; it < 8; ++it) {
        const int idx  = it * 256 + tid;
        const int rr   = idx >> 5;
        const int part = idx & 31;
        uint4* dst = reinterpret_cast<uint4*>(
            x5 + ((size_t)(t0m + rr) * 64 + b) * 768 + g * 256) + part;
        *dst = eps[idx];
    }
}

// ---------------------------------------------------------------------------
// Kernel 2: recurrence, HYBRID MFMA+VALU K-split. 64 blocks x 1 batch,
// 512 threads (8 waves, 2/SIMD).
//   MFMA covers K in [0,128): per wave phase1 16 instr, phase2 8.
//     (per-SIMD matrix-pipe: 48 x 19.4 cyc = 931, half of r5's 1862)
//   VALU dot2 covers K in [128,256): lane (gate=lane>>5, col=w*32+(lane&31))
//     does 64 dot2 in phase1; phase2 splits its 64-pair range across the
//     two half-waves (q=lane>>5) with a shfl_xor(32) merge. Operand H/R
//     chunks come from LDS via same-address-broadcast uint4 reads.
//   Merge is lane-local: the lane's (gate,col) epilogue duty matches its
//   MFMA D[0] fragment column, so v = mfma_part + valu_part. Pipes overlap
//   (m114): matrix 931/SIMD, VALU ~550/SIMD, LDS-broadcast ~1000/CU.
// ---------------------------------------------------------------------------
#define XB_U16 768  // 3*256 per (t,b)

__global__ __launch_bounds__(512, 1) void gru_recur(
    const ushort_t* __restrict__ x5,   // [t][b][g][j] bf16
    const ushort_t* __restrict__ Tz, const ushort_t* __restrict__ Tr,
    const ushort_t* __restrict__ Th,
    const uint_t* __restrict__ Pz, const uint_t* __restrict__ Pr,
    const uint_t* __restrict__ Ph,
    float* __restrict__ out)           // [B][T][256] then H_last [B][256]
{
    __shared__ __align__(16) ushort_t Hl[264];
    __shared__ __align__(16) ushort_t Rl[264];
    __shared__ __align__(16) ushort_t Xb[2][XB_U16];

    const int tid  = threadIdx.x;
    const int lane = tid & 63;
    const int w    = tid >> 6;      // wave 0..7
    const int kq   = lane >> 4;     // frag k-quadrant
    const int ml   = lane & 15;     // frag position
    const int cl   = lane & 31;     // epilogue column within wave
    const int gate = lane >> 5;     // 0: z-duty, 1: r-duty (== q in phase 2)
    const int sel  = (lane >> 4) & 1;
    const int j    = w * 32 + cl;   // hidden column this lane handles
    const int b    = blockIdx.x;    // batch 0..63

    // ---- MFMA weights, K<128 only: 3 x 2 tiles x 4 ktiles x 4 = 96 regs ----
    sh8 wz[2][4], wr[2][4], wh[2][4];
#pragma unroll
    for (int cc = 0; cc < 2; ++cc) {
        const int jw = w * 32 + cc * 16 + ml;
        const size_t rb = (size_t)jw * 256 + kq * 8;
#pragma unroll
        for (int kt = 0; kt < 4; ++kt) {
            wz[cc][kt] = *reinterpret_cast<const sh8*>(Tz + rb + kt * 32);
            wr[cc][kt] = *reinterpret_cast<const sh8*>(Tr + rb + kt * 32);
            wh[cc][kt] = *reinterpret_cast<const sh8*>(Th + rb + kt * 32);
        }
    }
    // ---- VALU weights, pair-packed, K>=128 ----
    // phase1: this lane's (gate,col): pairs 64..127 -> 64 u32
    // phase2: this lane's (q,col):   pairs 64+q*32 .. +32 -> 32 u32
    uint_t vw1[64], vw2[32];
    {
        const uint_t* Pg = gate ? Pr : Pz;
#pragma unroll
        for (int i = 0; i < 64; ++i) vw1[i] = Pg[(size_t)(64 + i) * 256 + j];
#pragma unroll
        for (int i = 0; i < 32; ++i)
            vw2[i] = Ph[(size_t)(64 + gate * 32 + i) * 256 + j];
    }

    if (tid < 132) { ((uint_t*)Hl)[tid] = 0u; ((uint_t*)Rl)[tid] = 0u; }

    float hk = 0.f;  // lanes 0-31: H[b][j]

    if (tid < 96) async_g2l(x5 + (size_t)b * XB_U16 + tid * 8, &Xb[0][tid * 8]);
    asm volatile("s_waitcnt vmcnt(0)" ::: "memory");
    __syncthreads();

    const ushort_t* harow = Hl + kq * 8;
    const ushort_t* rarow = Rl + kq * 8;
    float* ob = out + (size_t)b * TT * HD;

    const fx4 zero4 = {0.f, 0.f, 0.f, 0.f};
    int cur = 0;
    for (int t = 0; t < TT; ++t) {
        {
            const int tn = (t < TT - 1) ? t + 1 : t;
            if (tid < 96)
                async_g2l(x5 + ((size_t)tn * 64 + b) * XB_U16 + tid * 8,
                          &Xb[cur ^ 1][tid * 8]);
        }
        const ushort_t* xc = Xb[cur];

        // hoisted loads (hidden under MFMA/dot issue)
        const float hsh  = __shfl(hk, cl);
        const float xg   = bf2f(xc[gate * 256 + j]);
        const float xh_r = bf2f(xc[512 + j]);

        // ---- phase 1: Z, R = sigmoid(x + H @ W) ----
        // MFMA half (K<128)
        fx4 az0 = zero4, az1 = zero4, ar0 = zero4, ar1 = zero4;
#pragma unroll
        for (int kt = 0; kt < 4; ++kt) {
            const sh8 a = *reinterpret_cast<const sh8*>(harow + kt * 32);
            az0 = mfma16(a, wz[0][kt], az0);
            az1 = mfma16(a, wz[1][kt], az1);
            ar0 = mfma16(a, wr[0][kt], ar0);
            ar1 = mfma16(a, wr[1][kt], ar1);
        }
        // VALU half (K>=128): 16 broadcast uint4 reads feed 64 dot2
        float va0 = 0.f, va1 = 0.f, va2 = 0.f, va3 = 0.f;
#pragma unroll
        for (int u = 0; u < 16; ++u) {
            const uint4 hv = *reinterpret_cast<const uint4*>(Hl + 128 + u * 8);
            va0 = dot2bf(vw1[4 * u + 0], hv.x, va0);
            va1 = dot2bf(vw1[4 * u + 1], hv.y, va1);
            va2 = dot2bf(vw1[4 * u + 2], hv.z, va2);
            va3 = dot2bf(vw1[4 * u + 3], hv.w, va3);
        }
        const float vval = (va0 + va1) + (va2 + va3);
        const float v0 = gate ? ar0[0] : az0[0];
        const float v1 = gate ? ar1[0] : az1[0];
        const float s  = sigm(xg + (sel ? v1 : v0) + vval);
        const float zreg = s;  // meaningful in lanes 0-31
        if (gate) Rl[j] = f2bf(s * hsh);
        BAR();  // R*H visible to all waves

        // ---- phase 2: H~ = tanh(xh + (R*H) @ Whh); blend ----
        fx4 ah0 = zero4, ah1 = zero4;
#pragma unroll
        for (int kt = 0; kt < 4; ++kt) {
            const sh8 a = *reinterpret_cast<const sh8*>(rarow + kt * 32);
            ah0 = mfma16(a, wh[0][kt], ah0);
            ah1 = mfma16(a, wh[1][kt], ah1);
        }
        float vb0 = 0.f, vb1 = 0.f, vb2 = 0.f, vb3 = 0.f;
#pragma unroll
        for (int u = 0; u < 8; ++u) {
            const uint4 rv = *reinterpret_cast<const uint4*>(
                Rl + 128 + gate * 64 + u * 8);
            vb0 = dot2bf(vw2[4 * u + 0], rv.x, vb0);
            vb1 = dot2bf(vw2[4 * u + 1], rv.y, vb1);
            vb2 = dot2bf(vw2[4 * u + 2], rv.z, vb2);
            vb3 = dot2bf(vw2[4 * u + 3], rv.w, vb3);
        }
        float vh = (vb0 + vb1) + (vb2 + vb3);
        vh += __shfl_xor(vh, 32);  // combine the two K-quarters
        float hn = hk;
        if (!gate) {  // lanes 0-31 finish their column
            const float va = (sel ? ah1[0] : ah0[0]) + vh;
            const float th = tanh_fast(xh_r + va);
            hn = zreg * hk + (1.f - zreg) * th;
            hk = hn;
            Hl[j] = f2bf(hn);
        }
        asm volatile("s_waitcnt vmcnt(0)" ::: "memory");  // x[t+1] staged
        BAR();  // H + x-buffer safe for next step

        if (!gate) ob[(size_t)t * HD + j] = hn;
        cur ^= 1;
    }

    if (!gate) out[(size_t)BB * TT * HD + (size_t)b * HD + j] = hk;
}

// ---------------------------------------------------------------------------
extern "C" void kernel_launch(void* const* d_in, const int* in_sizes, int n_in,
                              void* d_out, int out_size, void* d_ws, size_t ws_size,
                              hipStream_t stream) {
    const float* X   = (const float*)d_in[0];
    const float* Wxz = (const float*)d_in[1];
    const float* Whz = (const float*)d_in[2];
    const float* bz  = (const float*)d_in[3];
    const float* Wxr = (const float*)d_in[4];
    const float* Whr = (const float*)d_in[5];
    const float* br  = (const float*)d_in[6];
    const float* Wxh = (const float*)d_in[7];
    const float* Whh = (const float*)d_in[8];
    const float* bh  = (const float*)d_in[9];
    float* out = (float*)d_out;

    // ws layout: x5 (96MiB) | T (3x128KiB) | Thi/Tlo (6x128KiB) | P (3x128KiB)
    const size_t X5_BYTES = (size_t)TT * BB * 3 * 256 * 2;
    ushort_t* x5  = (ushort_t*)d_ws;
    ushort_t* Tz  = (ushort_t*)((char*)d_ws + X5_BYTES);
    ushort_t* Tr  = Tz + HD * HD;
    ushort_t* Th  = Tr + HD * HD;
    ushort_t* Thi = Th + HD * HD;            // 3 * 65536 u16
    ushort_t* Tlo = Thi + 3 * HD * HD;       // 3 * 65536 u16
    uint_t*   Pz  = (uint_t*)(Tlo + 3 * HD * HD);
    uint_t*   Pr  = Pz + 128 * HD;
    uint_t*   Ph  = Pr + 128 * HD;

    prepack_kernel<<<dim3(256, 6), 256, 0, stream>>>(
        Whz, Whr, Whh, Wxz, Wxr, Wxh, Tz, Tr, Th, Pz, Pr, Ph, Thi, Tlo);
    proj_mfma<<<dim3(1024, 3), 256, 0, stream>>>(
        X, Thi, Tlo, bz, br, bh, x5);
    gru_recur<<<dim3(64), 512, 0, stream>>>(x5, Tz, Tr, Th, Pz, Pr, Ph, out);
}

// Round 7
// 1426.187 us; speedup vs baseline: 1.3878x; 1.3878x over previous
//
#include <hip/hip_runtime.h>
#include <math.h>

#define BB 64
#define TT 1024
#define II 256
#define HD 256

typedef unsigned short ushort_t;
typedef unsigned int uint_t;

// MFMA fragment types
typedef short sh8 __attribute__((ext_vector_type(8)));
typedef float fx4 __attribute__((ext_vector_type(4)));

// ---- bf16 helpers (manual, RNE) -------------------------------------------
__device__ __forceinline__ ushort_t f2bf(float f) {
    uint_t u = __float_as_uint(f);
    uint_t r = (u + 0x7fffu + ((u >> 16) & 1u)) >> 16;
    return (ushort_t)r;
}
__device__ __forceinline__ float bf2f(ushort_t v) {
    return __uint_as_float(((uint_t)v) << 16);
}

__device__ __forceinline__ float fast_rcp(float x) {
#if __has_builtin(__builtin_amdgcn_rcpf)
    return __builtin_amdgcn_rcpf(x);
#else
    return 1.f / x;
#endif
}
__device__ __forceinline__ float sigm(float x) {
    return fast_rcp(1.f + __expf(-x));
}
__device__ __forceinline__ float tanh_fast(float x) {
    return 1.f - 2.f * fast_rcp(1.f + __expf(2.f * x));
}

__device__ __forceinline__ fx4 mfma16(sh8 a, sh8 b, fx4 c) {
    return __builtin_amdgcn_mfma_f32_16x16x32_bf16(a, b, c, 0, 0, 0);
}

// split fp32 pair -> bf16 hi (trunc) + bf16 lo (residual) packed u32s
__device__ __forceinline__ void split2(float a, float b, uint_t& hi, uint_t& lo) {
    const uint_t ua = __float_as_uint(a), ub = __float_as_uint(b);
    hi = (ua >> 16) | (ub & 0xffff0000u);
    const float la = a - __uint_as_float(ua & 0xffff0000u);
    const float lb = b - __uint_as_float(ub & 0xffff0000u);
    const uint_t ula = __float_as_uint(la), ulb = __float_as_uint(lb);
    lo = (ula >> 16) | (ulb & 0xffff0000u);
}

// async global->LDS, 16B per lane
__device__ __forceinline__ void async_g2l(const ushort_t* g, ushort_t* l) {
#if __has_builtin(__builtin_amdgcn_global_load_lds)
    __builtin_amdgcn_global_load_lds(
        (const __attribute__((address_space(1))) unsigned int*)g,
        (__attribute__((address_space(3))) unsigned int*)l, 16, 0, 0);
#else
    *reinterpret_cast<uint4*>(l) = *reinterpret_cast<const uint4*>(g);
#endif
}

#define BAR() asm volatile("s_waitcnt lgkmcnt(0)\n\ts_barrier" ::: "memory")

// ---------------------------------------------------------------------------
// Kernel 0: prepack weights (r5-identical).
//  y=0..2: recurrent W fp32 [k][j] -> bf16 W^T  T[j*256+k]
//  y=3..5: input Wx fp32 -> split bf16 hi/lo W^T (proj_fused)
// ---------------------------------------------------------------------------
__global__ __launch_bounds__(256) void prepack_kernel(
    const float* __restrict__ Wz, const float* __restrict__ Wr,
    const float* __restrict__ Wh,
    const float* __restrict__ Xz, const float* __restrict__ Xr,
    const float* __restrict__ Xh,
    ushort_t* __restrict__ Tz, ushort_t* __restrict__ Tr,
    ushort_t* __restrict__ Th,
    ushort_t* __restrict__ Thi, ushort_t* __restrict__ Tlo)
{
    const int idx = blockIdx.x * 256 + threadIdx.x;  // 0..65535
    const int j = idx >> 8;
    const int k = idx & 255;
    const int y = blockIdx.y;
    if (y < 3) {
        const float* W = (y == 0) ? Wz : (y == 1) ? Wr : Wh;
        ushort_t* T = (y == 0) ? Tz : (y == 1) ? Tr : Th;
        T[idx] = f2bf(W[k * HD + j]);
    } else {
        const int g = y - 3;
        const float* W = (g == 0) ? Xz : (g == 1) ? Xr : Xh;
        const float wv = W[k * HD + j];
        const ushort_t hi = f2bf(wv);
        Thi[g * 65536 + idx] = hi;
        Tlo[g * 65536 + idx] = f2bf(wv - bf2f(hi));
    }
}

// ---------------------------------------------------------------------------
// Kernel 1: gate-FUSED input projection, 3-term split-precision bf16 MFMA.
// Block = 32 t-rows of one batch x ALL 3 gates. X read once, split2 once,
// hi/lo staged in LDS [2][32][264] (16B-aligned rows, 2-way-free banks).
// 8 waves: wave w owns cols w*32..+31 (2 n-tiles) x 2 m-tiles x 3 gates.
// acc[3][2][2] = 48 VGPRs. Same term order per output as r5 -> bit-identical.
// Grid is t-major (bx = tc*64 + b) for future proj/gru overlap.
// ---------------------------------------------------------------------------
#define XROW 264  // u16 per LDS row: 256 + 8 pad (528B stride, 16B multiple)

__global__ __launch_bounds__(512) void proj_fused(
    const float* __restrict__ X,
    const ushort_t* __restrict__ Thi, const ushort_t* __restrict__ Tlo,
    const float* __restrict__ bz, const float* __restrict__ br,
    const float* __restrict__ bh,
    ushort_t* __restrict__ x5)
{
    __shared__ __align__(16) ushort_t Xs[2][32][XROW];  // hi/lo, 33.8KB
    __shared__ __align__(16) ushort_t ep[32 * 256];     // 16KB

    const int tid  = threadIdx.x;
    const int lane = tid & 63;
    const int w    = tid >> 6;       // wave 0..7: col slice w*32..+31
    const int kq   = lane >> 4;
    const int ml   = lane & 15;
    const int b    = blockIdx.x & 63;
    const int tc   = blockIdx.x >> 6;   // 0..31
    const int t0   = tc * 32;

    // ---- load X rows [32][256] fp32, split -> Xs hi/lo ----
#pragma unroll
    for (int i = 0; i < 4; ++i) {
        const int idx = i * 512 + tid;   // 0..2047 float4s
        const int r   = idx >> 6;        // row 0..31
        const int c4  = idx & 63;        // float4 col
        const float4 v = *reinterpret_cast<const float4*>(
            X + (size_t)(b * 1024 + t0 + r) * II + c4 * 4);
        uint_t h0, l0, h1, l1;
        split2(v.x, v.y, h0, l0);
        split2(v.z, v.w, h1, l1);
        *reinterpret_cast<uint_t*>(&Xs[0][r][c4 * 4])     = h0;
        *reinterpret_cast<uint_t*>(&Xs[0][r][c4 * 4 + 2]) = h1;
        *reinterpret_cast<uint_t*>(&Xs[1][r][c4 * 4])     = l0;
        *reinterpret_cast<uint_t*>(&Xs[1][r][c4 * 4 + 2]) = l1;
    }
    __syncthreads();

    const fx4 zero4 = {0.f, 0.f, 0.f, 0.f};
    fx4 acc[3][2][2];  // [g][mt][nt]
#pragma unroll
    for (int g = 0; g < 3; ++g)
#pragma unroll
        for (int mt = 0; mt < 2; ++mt)
#pragma unroll
            for (int nt = 0; nt < 2; ++nt) acc[g][mt][nt] = zero4;

#pragma unroll
    for (int kt = 0; kt < 8; ++kt) {
        const int koff = kq * 8 + kt * 32;
        sh8 ahi[2], alo[2];
#pragma unroll
        for (int mt = 0; mt < 2; ++mt) {
            ahi[mt] = *reinterpret_cast<const sh8*>(&Xs[0][mt * 16 + ml][koff]);
            alo[mt] = *reinterpret_cast<const sh8*>(&Xs[1][mt * 16 + ml][koff]);
        }
#pragma unroll
        for (int g = 0; g < 3; ++g) {
            sh8 bhi[2], blo[2];
#pragma unroll
            for (int nt = 0; nt < 2; ++nt) {
                const size_t rb = ((size_t)g << 16) +
                    (size_t)(w * 32 + nt * 16 + ml) * 256 + koff;
                bhi[nt] = *reinterpret_cast<const sh8*>(Thi + rb);
                blo[nt] = *reinterpret_cast<const sh8*>(Tlo + rb);
            }
#pragma unroll
            for (int mt = 0; mt < 2; ++mt)
#pragma unroll
                for (int nt = 0; nt < 2; ++nt) {
                    acc[g][mt][nt] = mfma16(ahi[mt], bhi[nt], acc[g][mt][nt]);
                    acc[g][mt][nt] = mfma16(alo[mt], bhi[nt], acc[g][mt][nt]);
                    acc[g][mt][nt] = mfma16(ahi[mt], blo[nt], acc[g][mt][nt]);
                }
        }
    }

    // ---- epilogue per gate: bias + bf16 via 16KB ep staging ----
    for (int g = 0; g < 3; ++g) {
        const float* bias = (g == 0) ? bz : (g == 1) ? br : bh;
        __syncthreads();  // ep free for reuse
#pragma unroll
        for (int nt = 0; nt < 2; ++nt) {
            const int col = w * 32 + nt * 16 + ml;
            const float bv = bias[col];
#pragma unroll
            for (int mt = 0; mt < 2; ++mt)
#pragma unroll
                for (int r = 0; r < 4; ++r)
                    ep[(mt * 16 + kq * 4 + r) * 256 + col] =
                        f2bf(acc[g][mt][nt][r] + bv);
        }
        __syncthreads();
        const uint4* eps = reinterpret_cast<const uint4*>(ep);
#pragma unroll
        for (int it = 0; it < 2; ++it) {
            const int idx  = it * 512 + tid;  // 0..1023
            const int rr   = idx >> 5;        // row 0..31
            const int part = idx & 31;        // 32 x 16B = 512B per row
            uint4* dst = reinterpret_cast<uint4*>(
                x5 + ((size_t)(t0 + rr) * 64 + b) * 768 + g * 256) + part;
            *dst = eps[idx];
        }
    }
}

// ---------------------------------------------------------------------------
// Kernel 2: recurrence (r5-identical, measured 1147us). 64 blocks x 1 batch,
// 512 threads (8 waves); wave owns 32 cols (2 tiles); 48 mfma/wave/step.
// A-frag rows all duplicates -> broadcast LDS reads, shuffle-free epilogue.
// ---------------------------------------------------------------------------
#define XB_U16 768  // 3*256 per (t,b)

__global__ __launch_bounds__(512, 1) void gru_recur(
    const ushort_t* __restrict__ x5,   // [t][b][g][j] bf16
    const ushort_t* __restrict__ Tz, const ushort_t* __restrict__ Tr,
    const ushort_t* __restrict__ Th,
    float* __restrict__ out)           // [B][T][256] then H_last [B][256]
{
    __shared__ __align__(16) ushort_t Hl[264];
    __shared__ __align__(16) ushort_t Rl[264];
    __shared__ __align__(16) ushort_t Xb[2][XB_U16];

    const int tid  = threadIdx.x;
    const int lane = tid & 63;
    const int w    = tid >> 6;      // wave 0..7
    const int kq   = lane >> 4;     // frag k-quadrant
    const int ml   = lane & 15;     // frag position
    const int cl   = lane & 31;     // epilogue column within wave
    const int gate = lane >> 5;     // 0: z-duty, 1: r-duty
    const int sel  = (lane >> 4) & 1;  // which tile's acc reg
    const int j    = w * 32 + cl;   // hidden column this lane handles
    const int b    = blockIdx.x;    // batch 0..63

    // ---- all three W^T in regs: 3 x 2 x 8 x 4 = 192 ----
    sh8 wz[2][8], wr[2][8], wh[2][8];
#pragma unroll
    for (int cc = 0; cc < 2; ++cc) {
        const int jw = w * 32 + cc * 16 + ml;
        const size_t rb = (size_t)jw * 256 + kq * 8;
#pragma unroll
        for (int kt = 0; kt < 8; ++kt) {
            wz[cc][kt] = *reinterpret_cast<const sh8*>(Tz + rb + kt * 32);
            wr[cc][kt] = *reinterpret_cast<const sh8*>(Tr + rb + kt * 32);
            wh[cc][kt] = *reinterpret_cast<const sh8*>(Th + rb + kt * 32);
        }
    }

    if (tid < 132) { ((uint_t*)Hl)[tid] = 0u; ((uint_t*)Rl)[tid] = 0u; }

    float hk = 0.f;  // lanes 0-31: H[b][j]; lanes 32-63 unused

    if (tid < 96) async_g2l(x5 + (size_t)b * XB_U16 + tid * 8, &Xb[0][tid * 8]);
    asm volatile("s_waitcnt vmcnt(0)" ::: "memory");
    __syncthreads();

    const ushort_t* harow = Hl + kq * 8;
    const ushort_t* rarow = Rl + kq * 8;
    float* ob = out + (size_t)b * TT * HD;

    const fx4 zero4 = {0.f, 0.f, 0.f, 0.f};
    int cur = 0;
    for (int t = 0; t < TT; ++t) {
        {
            const int tn = (t < TT - 1) ? t + 1 : t;
            if (tid < 96)
                async_g2l(x5 + ((size_t)tn * 64 + b) * XB_U16 + tid * 8,
                          &Xb[cur ^ 1][tid * 8]);
        }
        const ushort_t* xc = Xb[cur];

        // hoisted: h[j] into r-lanes + x reads; hidden under phase-1 MFMAs
        const float hsh  = __shfl(hk, cl);
        const float xg   = bf2f(xc[gate * 256 + j]);
        const float xh_r = bf2f(xc[512 + j]);

        // ---- phase 1: Z, R = sigmoid(x + H @ W) ----
        fx4 az0 = zero4, az1 = zero4, ar0 = zero4, ar1 = zero4;
#pragma unroll
        for (int kt = 0; kt < 8; ++kt) {
            const sh8 a = *reinterpret_cast<const sh8*>(harow + kt * 32);
            az0 = mfma16(a, wz[0][kt], az0);
            az1 = mfma16(a, wz[1][kt], az1);
            ar0 = mfma16(a, wr[0][kt], ar0);
            ar1 = mfma16(a, wr[1][kt], ar1);
        }
        const float v0 = gate ? ar0[0] : az0[0];
        const float v1 = gate ? ar1[0] : az1[0];
        const float v  = sel ? v1 : v0;
        const float s  = sigm(xg + v);
        const float zreg = s;  // meaningful in lanes 0-31
        if (gate) Rl[j] = f2bf(s * hsh);
        BAR();  // R*H visible to all waves

        // ---- phase 2: H~ = tanh(xh + (R*H) @ Whh); blend ----
        fx4 ah0a = zero4, ah0b = zero4, ah1a = zero4, ah1b = zero4;
#pragma unroll
        for (int kt = 0; kt < 8; kt += 2) {
            const sh8 a0 = *reinterpret_cast<const sh8*>(rarow + kt * 32);
            const sh8 a1 = *reinterpret_cast<const sh8*>(rarow + (kt + 1) * 32);
            ah0a = mfma16(a0, wh[0][kt], ah0a);
            ah1a = mfma16(a0, wh[1][kt], ah1a);
            ah0b = mfma16(a1, wh[0][kt + 1], ah0b);
            ah1b = mfma16(a1, wh[1][kt + 1], ah1b);
        }
        float hn = hk;
        if (!gate) {  // lanes 0-31 finish their column
            const float va = sel ? (ah1a[0] + ah1b[0]) : (ah0a[0] + ah0b[0]);
            const float th = tanh_fast(xh_r + va);
            hn = zreg * hk + (1.f - zreg) * th;
            hk = hn;
            Hl[j] = f2bf(hn);
        }
        asm volatile("s_waitcnt vmcnt(0)" ::: "memory");  // x[t+1] staged
        BAR();  // H + x-buffer safe for next step

        if (!gate) ob[(size_t)t * HD + j] = hn;
        cur ^= 1;
    }

    if (!gate) out[(size_t)BB * TT * HD + (size_t)b * HD + j] = hk;
}

// ---------------------------------------------------------------------------
extern "C" void kernel_launch(void* const* d_in, const int* in_sizes, int n_in,
                              void* d_out, int out_size, void* d_ws, size_t ws_size,
                              hipStream_t stream) {
    const float* X   = (const float*)d_in[0];
    const float* Wxz = (const float*)d_in[1];
    const float* Whz = (const float*)d_in[2];
    const float* bz  = (const float*)d_in[3];
    const float* Wxr = (const float*)d_in[4];
    const float* Whr = (const float*)d_in[5];
    const float* br  = (const float*)d_in[6];
    const float* Wxh = (const float*)d_in[7];
    const float* Whh = (const float*)d_in[8];
    const float* bh  = (const float*)d_in[9];
    float* out = (float*)d_out;

    // ws layout: x5 (96MiB) | Tz/Tr/Th (3x128KiB) | Thi (384KiB) | Tlo (384KiB)
    const size_t X5_BYTES = (size_t)TT * BB * 3 * 256 * 2;
    ushort_t* x5  = (ushort_t*)d_ws;
    ushort_t* Tz  = (ushort_t*)((char*)d_ws + X5_BYTES);
    ushort_t* Tr  = Tz + HD * HD;
    ushort_t* Th  = Tr + HD * HD;
    ushort_t* Thi = Th + HD * HD;            // 3 * 65536 u16
    ushort_t* Tlo = Thi + 3 * HD * HD;       // 3 * 65536 u16

    prepack_kernel<<<dim3(256, 6), 256, 0, stream>>>(
        Whz, Whr, Whh, Wxz, Wxr, Wxh, Tz, Tr, Th, Thi, Tlo);
    proj_fused<<<dim3(2048), 512, 0, stream>>>(
        X, Thi, Tlo, bz, br, bh, x5);
    gru_recur<<<dim3(64), 512, 0, stream>>>(x5, Tz, Tr, Th, out);
}